// Round 5
// baseline (255.051 us; speedup 1.0000x reference)
//
#include <hip/hip_runtime.h>

#define EDIM 300
#define NB   128
#define NQ   16
#define ND   1024
#define NK   11
#define BLOCK 256
#define TDOCS 256                 // docs per block
#define BLOCKS_PER_B 4            // 1024 / 256
#define DTILE 32                  // docs per staged tile (full 300-float rows)
#define NTILE 8                   // TDOCS / DTILE
#define NF4   75                  // float4 per embedding row (300/4)

// R13: attack the DRAM access-granularity wall. R8-R12 post-mortem: every
// schedule (reg-prefetch, lgkm-only barriers, 2 waves/SIMD) landed at 69-77us
// with gather BW pinned at 1.3-1.4 TB/s while fills stream 6.8 TB/s, and
// FETCH_SIZE already at the compulsory ~99MB floor. The E-panel structure
// visits each random 1200B row 10 times x 128B, ~7us apart -> row-activation-
// bound scatter. Fix: doc-tile staging — each tile stages 32 FULL rows as
// contiguous 1200B bursts via global_load_lds (per-lane global src, linear
// LDS dest = uniform base + lane*16; packed [32][300] layout is 2-way-bank-max
// since 300%32=12). Compute: lane=(doc pair, E-quarter), wave=q-quad; quarter
// dots combined via shfl_xor(16/32); RBF kernel bank split across quarter
// groups (g*3..g*3+2) so no lane is idle; reduce over doc lanes at the end.

__device__ __forceinline__ void gload16(const float* g, float* l) {
    __builtin_amdgcn_global_load_lds(
        (const __attribute__((address_space(1))) void*)g,
        (__attribute__((address_space(3))) void*)l, 16, 0, 0);
}

__global__ __launch_bounds__(BLOCK, 2) void knrm_main(
    const int*   __restrict__ dtoks,
    const int*   __restrict__ qtoks,
    const float* __restrict__ emb,
    const float* __restrict__ mus,
    const float* __restrict__ sigmas,
    float*       __restrict__ part) {
    __shared__ __align__(16) float qn_s[NQ * EDIM];      // 19.2 KB, packed [16][300]
    __shared__ __align__(16) float dpan[DTILE * EDIM];   // 38.4 KB, packed [32][300]
    __shared__ int   dtok_s[TDOCS];                      // 1 KB
    __shared__ float rs_s[NQ];
    // total ~58.7 KB -> 2 blocks/CU, 8 waves/CU, 2 waves/SIMD

    const int blk   = blockIdx.x;
    const int b     = blk >> 2;
    const int dbase = (blk & 3) * TDOCS;
    const int tid   = threadIdx.x;
    const int lane  = tid & 63;
    const int w     = tid >> 6;          // q-quad (wave-uniform): q = w*4+qq

    // ---- doc-token tile + q rows (q rows via full-row gload_lds bursts) ----
    dtok_s[tid] = dtoks[b * ND + dbase + tid];           // BLOCK == TDOCS
#pragma unroll
    for (int i = 0; i < 5; ++i) {                        // 16 rows * 75 f4 = 1200 slots
        if (i < 4 || lane < 44) {                        // per-wave 300 slots
            int fi = w * 300 + i * 64 + lane;
            int q = fi / NF4, e4 = fi - q * NF4;
            gload16(emb + (size_t)qtoks[b * NQ + q] * EDIM + e4 * 4, qn_s + fi * 4);
        }
    }
    __syncthreads();                     // dtok_s visible, q rows landed (vmcnt drain)

    // ---- issue tile-0 stage (overlaps qnorm) ----
    // stage(tb): 32 rows * 75 f4 = 2400 slots; per wave 600; consecutive lanes
    // cover consecutive 16B within a row -> full-row DRAM bursts.
#define STAGE(tb) do {                                                         \
    _Pragma("unroll")                                                          \
    for (int i_ = 0; i_ < 10; ++i_) {                                          \
        if (i_ < 9 || lane < 24) {                                             \
            int fi_ = w * 600 + i_ * 64 + lane;                                \
            int r_ = fi_ / NF4, e4_ = fi_ - r_ * NF4;                          \
            gload16(emb + (size_t)dtok_s[(tb) * DTILE + r_] * EDIM + e4_ * 4,  \
                    dpan + fi_ * 4);                                           \
        }                                                                      \
    } } while (0)

    STAGE(0);

    {   // q norms: 16 lanes per q
        int q = tid >> 4, j = tid & 15;
        float ss = 0.f;
        for (int e = j; e < EDIM; e += 16) { float v = qn_s[q * EDIM + e]; ss += v * v; }
        ss += __shfl_xor(ss, 1, 64);
        ss += __shfl_xor(ss, 2, 64);
        ss += __shfl_xor(ss, 4, 64);
        ss += __shfl_xor(ss, 8, 64);
        if (j == 0) rs_s[q] = 1.0f / (sqrtf(ss) + 1e-9f);
    }
    __syncthreads();                     // rs_s visible
    for (int i = tid; i < NQ * NF4; i += BLOCK) {        // scale q rows (1200 f4)
        float4 v = ((float4*)qn_s)[i];
        float r = rs_s[i / NF4];
        v.x *= r; v.y *= r; v.z *= r; v.w *= r;
        ((float4*)qn_s)[i] = v;
    }

    // ---- per-thread roles for compute ----
    const int d    = lane & 15;          // doc pair base within tile (d, d+16)
    const int g    = lane >> 4;          // E-quarter AND kernel-bank group (0..3)
    const int e4lo = g * 19;             // quarter e4 range [g*19, min(g*19+19,75))

    float mu[3], c2[3];
#pragma unroll
    for (int j = 0; j < 3; ++j) {
        int kk = g * 3 + j; if (kk > NK - 1) kk = NK - 1;   // g=3,j=2 dup of k10 (not written)
        mu[j] = mus[kk];
        float sg = sigmas[kk];
        c2[j] = -0.5f / (sg * sg);
    }
    float racc[12];
#pragma unroll
    for (int t = 0; t < 12; ++t) racc[t] = 0.f;

    for (int tb = 0; tb < NTILE; ++tb) {
        __syncthreads();                 // stage(tb) landed (vmcnt drained at barrier),
                                         // scaled qn_s visible (tb=0), prev compute done
        float sv[2][4], ssq[2];
#pragma unroll
        for (int m = 0; m < 2; ++m) { ssq[m] = 0.f;
#pragma unroll
            for (int qq = 0; qq < 4; ++qq) sv[m][qq] = 0.f; }

        const float* dr0 = dpan + d * EDIM;
        const float* dr1 = dpan + (d + 16) * EDIM;
        const float* qb  = qn_s + (w * 4) * EDIM;
#pragma unroll
        for (int i = 0; i < 19; ++i) {
            int e4 = e4lo + i;
            if (e4 < NF4) {              // masks only the g==3 19th iter
                float4 a = *(const float4*)(dr0 + e4 * 4);
                float4 c = *(const float4*)(dr1 + e4 * 4);
                ssq[0] += a.x*a.x + a.y*a.y + a.z*a.z + a.w*a.w;
                ssq[1] += c.x*c.x + c.y*c.y + c.z*c.z + c.w*c.w;
#pragma unroll
                for (int qq = 0; qq < 4; ++qq) {
                    float4 qv = *(const float4*)(qb + qq * EDIM + e4 * 4); // phase-broadcast
                    sv[0][qq] += qv.x*a.x + qv.y*a.y + qv.z*a.z + qv.w*a.w;
                    sv[1][qq] += qv.x*c.x + qv.y*c.y + qv.z*c.z + qv.w*c.w;
                }
            }
        }
        // combine the 4 E-quarters (xor 16, 32 stay within the wave)
#pragma unroll
        for (int m = 0; m < 2; ++m) {
            ssq[m] += __shfl_xor(ssq[m], 16, 64);
            ssq[m] += __shfl_xor(ssq[m], 32, 64);
#pragma unroll
            for (int qq = 0; qq < 4; ++qq) {
                sv[m][qq] += __shfl_xor(sv[m][qq], 16, 64);
                sv[m][qq] += __shfl_xor(sv[m][qq], 32, 64);
            }
        }
        float rn0 = 1.0f / (sqrtf(ssq[0]) + 1e-9f);
        float rn1 = 1.0f / (sqrtf(ssq[1]) + 1e-9f);
        // RBF: each quarter-group handles kernels g*3..g*3+2 for both docs
#pragma unroll
        for (int qq = 0; qq < 4; ++qq) {
            float s0 = sv[0][qq] * rn0;
            float s1 = sv[1][qq] * rn1;
#pragma unroll
            for (int j = 0; j < 3; ++j) {
                float e0 = s0 - mu[j], e1 = s1 - mu[j];
                racc[j * 4 + qq] += __expf(c2[j] * e0 * e0) + __expf(c2[j] * e1 * e1);
            }
        }
        __syncthreads();                 // dpan fully consumed
        if (tb + 1 < NTILE) STAGE(tb + 1);   // async; drains at next loop-top barrier
    }

    // ---- reduce over the 16 doc lanes, write per-block partials ----
#pragma unroll
    for (int t = 0; t < 12; ++t) {
        racc[t] += __shfl_xor(racc[t], 1, 64);
        racc[t] += __shfl_xor(racc[t], 2, 64);
        racc[t] += __shfl_xor(racc[t], 4, 64);
        racc[t] += __shfl_xor(racc[t], 8, 64);
    }
    if ((lane & 15) == 0) {
        const int kb = g * 3;
#pragma unroll
        for (int j = 0; j < 3; ++j) {
            if (g < 3 || j < 2) {        // skip the k10 duplicate slot
#pragma unroll
                for (int qq = 0; qq < 4; ++qq)
                    part[blk * (NK * NQ) + (kb + j) * NQ + (w * 4 + qq)] = racc[j * 4 + qq];
            }
        }
    }
}

// ---------------- Kernel 2: sum partials, masked log-sum over q, FC ----------------
__global__ void knrm_final(const float* __restrict__ part,
                           const int*   __restrict__ qtoks,
                           const float* __restrict__ fc_w,
                           const float* __restrict__ fc_b,
                           float*       __restrict__ out) {
    __shared__ float red[NK * NQ];
    __shared__ float ks[NK];
    int b = blockIdx.x;
    int t = threadIdx.x;
    if (t < NK * NQ) {
        int q = t & 15;
        float r = 0.f;
        for (int j = 0; j < BLOCKS_PER_B; ++j)
            r += part[(b * BLOCKS_PER_B + j) * (NK * NQ) + t];
        red[t] = (qtoks[b * NQ + q] != 0) ? logf(r + 1e-6f) : 0.f;
    }
    __syncthreads();
    if (t < NK) {
        float s = 0.f;
        for (int q = 0; q < NQ; ++q) s += red[t * NQ + q];
        ks[t] = s * fc_w[t];
    }
    __syncthreads();
    if (t == 0) {
        float s = fc_b[0];
        for (int k = 0; k < NK; ++k) s += ks[k];
        out[b] = s;
    }
}

extern "C" void kernel_launch(void* const* d_in, const int* in_sizes, int n_in,
                              void* d_out, int out_size, void* d_ws, size_t ws_size,
                              hipStream_t stream) {
    const int*   doctoks   = (const int*)  d_in[0];   // [128,1024]
    const int*   querytoks = (const int*)  d_in[1];   // [128,16]
    // d_in[2] = query_idf: unused by the reference
    const float* emb       = (const float*)d_in[3];   // [100000,300]
    const float* mus       = (const float*)d_in[4];   // [11]
    const float* sigmas    = (const float*)d_in[5];   // [11]
    const float* fc_w      = (const float*)d_in[6];   // [1,11]
    const float* fc_b      = (const float*)d_in[7];   // [1]
    float* out = (float*)d_out;                        // [128]

    float* part = (float*)d_ws;                        // [512][176] floats

    knrm_main<<<NB * BLOCKS_PER_B, BLOCK, 0, stream>>>(doctoks, querytoks, emb,
                                                       mus, sigmas, part);
    knrm_final<<<NB, 192, 0, stream>>>(part, querytoks, fc_w, fc_b, out);
}

// Round 6
// 245.918 us; speedup vs baseline: 1.0371x; 1.0371x over previous
//
#include <hip/hip_runtime.h>

#define EDIM 300
#define NB   128
#define NQ   16
#define ND   1024
#define NK   11
#define BLOCK 256
#define TDOCS 256                 // docs per block
#define BLOCKS_PER_B 4            // 1024 / 256
#define DTILE 32                  // docs per staged tile (full 300-float rows)
#define NTILE 8                   // TDOCS / DTILE
#define NF4   75                  // float4 per embedding row (300/4)

// R14: fix R13's pipeline bug. R13 issued STAGE(t+1) at the loop BOTTOM and the
// next loop-top __syncthreads (vmcnt(0) drain) hit it immediately -> zero
// overlap, BW still 1.4 TB/s, +33% FETCH -> 112us. Fix: DOUBLE-buffer dpan and
// issue STAGE(t+1 -> other buf) right AFTER the loop-top barrier, BEFORE
// compute(t): the stage is then in flight across the whole ~0.85us compute
// phase, and the next barrier's vmcnt drain is free (loads are old). Plain
// __syncthreads everywhere — the barrier that frees the other buffer is the
// same barrier we stage after. Compute/RBF identical to R13 (verified absmax 0).
// LDS ~97KB -> 1 block/CU, 4 waves; latency hidden by pipeline, not TLP.

__device__ __forceinline__ void gload16(const float* g, float* l) {
    __builtin_amdgcn_global_load_lds(
        (const __attribute__((address_space(1))) void*)g,
        (__attribute__((address_space(3))) void*)l, 16, 0, 0);
}

__global__ __launch_bounds__(BLOCK, 1) void knrm_main(
    const int*   __restrict__ dtoks,
    const int*   __restrict__ qtoks,
    const float* __restrict__ emb,
    const float* __restrict__ mus,
    const float* __restrict__ sigmas,
    float*       __restrict__ part) {
    __shared__ __align__(16) float qn_s[NQ * EDIM];        // 19.2 KB, packed [16][300]
    __shared__ __align__(16) float dpan[2][DTILE * EDIM];  // 76.8 KB, packed [32][300] x2
    __shared__ int   dtok_s[TDOCS];                        // 1 KB
    __shared__ float rs_s[NQ];
    // total ~97.1 KB -> 1 block/CU, 4 waves

    const int blk   = blockIdx.x;
    const int b     = blk >> 2;
    const int dbase = (blk & 3) * TDOCS;
    const int tid   = threadIdx.x;
    const int lane  = tid & 63;
    const int w     = tid >> 6;          // q-quad (wave-uniform): q = w*4+qq

    // ---- doc-token tile + q rows (full-row gload_lds bursts) ----
    dtok_s[tid] = dtoks[b * ND + dbase + tid];           // BLOCK == TDOCS
#pragma unroll
    for (int i = 0; i < 5; ++i) {                        // 16 rows * 75 f4 = 1200 slots
        if (i < 4 || lane < 44) {                        // per-wave 300 slots
            int fi = w * 300 + i * 64 + lane;
            int q = fi / NF4, e4 = fi - q * NF4;
            gload16(emb + (size_t)qtoks[b * NQ + q] * EDIM + e4 * 4, qn_s + fi * 4);
        }
    }

    // stage(tb -> dst): 32 rows * 75 f4 = 2400 slots; 600/wave (10 instrs, last
    // lane<24); consecutive lanes cover consecutive 16B within a row.
#define STAGE(tb, dst) do {                                                    \
    _Pragma("unroll")                                                          \
    for (int i_ = 0; i_ < 10; ++i_) {                                          \
        if (i_ < 9 || lane < 24) {                                             \
            int fi_ = w * 600 + i_ * 64 + lane;                                \
            int r_ = fi_ / NF4, e4_ = fi_ - r_ * NF4;                          \
            gload16(emb + (size_t)dtok_s[(tb) * DTILE + r_] * EDIM + e4_ * 4,  \
                    (dst) + fi_ * 4);                                          \
        }                                                                      \
    } } while (0)

    STAGE(0, dpan[0]);                   // in flight under qnorm phase

    __syncthreads();                     // q rows + tile0 landed, dtok_s visible
    {   // q norms: 16 lanes per q
        int q = tid >> 4, j = tid & 15;
        float ss = 0.f;
        for (int e = j; e < EDIM; e += 16) { float v = qn_s[q * EDIM + e]; ss += v * v; }
        ss += __shfl_xor(ss, 1, 64);
        ss += __shfl_xor(ss, 2, 64);
        ss += __shfl_xor(ss, 4, 64);
        ss += __shfl_xor(ss, 8, 64);
        if (j == 0) rs_s[q] = 1.0f / (sqrtf(ss) + 1e-9f);
    }
    __syncthreads();                     // rs_s visible
    for (int i = tid; i < NQ * NF4; i += BLOCK) {        // scale q rows (1200 f4)
        float4 v = ((float4*)qn_s)[i];
        float r = rs_s[i / NF4];
        v.x *= r; v.y *= r; v.z *= r; v.w *= r;
        ((float4*)qn_s)[i] = v;
    }
    // scaled qn_s made visible by the loop-top barrier of tb=0

    // ---- per-thread roles for compute ----
    const int d    = lane & 15;          // doc pair base within tile (d, d+16)
    const int g    = lane >> 4;          // E-quarter AND kernel-bank group (0..3)
    const int e4lo = g * 19;             // quarter e4 range [g*19, min(g*19+19,75))

    float mu[3], c2[3];
#pragma unroll
    for (int j = 0; j < 3; ++j) {
        int kk = g * 3 + j; if (kk > NK - 1) kk = NK - 1;   // g=3,j=2 dup of k10 (not written)
        mu[j] = mus[kk];
        float sg = sigmas[kk];
        c2[j] = -0.5f / (sg * sg);
    }
    float racc[12];
#pragma unroll
    for (int t = 0; t < 12; ++t) racc[t] = 0.f;

    for (int tb = 0; tb < NTILE; ++tb) {
        __syncthreads();                 // stage(tb) landed (free drain: it had all of
                                         // compute(tb-1) to land); compute(tb-1) done ->
                                         // other buffer free; scaled qn_s visible (tb=0)
        if (tb + 1 < NTILE)
            STAGE(tb + 1, dpan[(tb + 1) & 1]);   // in flight under compute(tb)

        const float* cur = dpan[tb & 1];
        float sv[2][4], ssq[2];
#pragma unroll
        for (int m = 0; m < 2; ++m) { ssq[m] = 0.f;
#pragma unroll
            for (int qq = 0; qq < 4; ++qq) sv[m][qq] = 0.f; }

        const float* dr0 = cur + d * EDIM;
        const float* dr1 = cur + (d + 16) * EDIM;
        const float* qb  = qn_s + (w * 4) * EDIM;
#pragma unroll
        for (int i = 0; i < 19; ++i) {
            int e4 = e4lo + i;
            if (e4 < NF4) {              // masks only the g==3 19th iter
                float4 a = *(const float4*)(dr0 + e4 * 4);
                float4 c = *(const float4*)(dr1 + e4 * 4);
                ssq[0] += a.x*a.x + a.y*a.y + a.z*a.z + a.w*a.w;
                ssq[1] += c.x*c.x + c.y*c.y + c.z*c.z + c.w*c.w;
#pragma unroll
                for (int qq = 0; qq < 4; ++qq) {
                    float4 qv = *(const float4*)(qb + qq * EDIM + e4 * 4); // broadcast
                    sv[0][qq] += qv.x*a.x + qv.y*a.y + qv.z*a.z + qv.w*a.w;
                    sv[1][qq] += qv.x*c.x + qv.y*c.y + qv.z*c.z + qv.w*c.w;
                }
            }
        }
        // combine the 4 E-quarters (xor 16, 32 stay within the wave)
#pragma unroll
        for (int m = 0; m < 2; ++m) {
            ssq[m] += __shfl_xor(ssq[m], 16, 64);
            ssq[m] += __shfl_xor(ssq[m], 32, 64);
#pragma unroll
            for (int qq = 0; qq < 4; ++qq) {
                sv[m][qq] += __shfl_xor(sv[m][qq], 16, 64);
                sv[m][qq] += __shfl_xor(sv[m][qq], 32, 64);
            }
        }
        float rn0 = 1.0f / (sqrtf(ssq[0]) + 1e-9f);
        float rn1 = 1.0f / (sqrtf(ssq[1]) + 1e-9f);
        // RBF: each quarter-group handles kernels g*3..g*3+2 for both docs
#pragma unroll
        for (int qq = 0; qq < 4; ++qq) {
            float s0 = sv[0][qq] * rn0;
            float s1 = sv[1][qq] * rn1;
#pragma unroll
            for (int j = 0; j < 3; ++j) {
                float e0 = s0 - mu[j], e1 = s1 - mu[j];
                racc[j * 4 + qq] += __expf(c2[j] * e0 * e0) + __expf(c2[j] * e1 * e1);
            }
        }
        // no bottom barrier: next loop-top barrier covers buffer reuse
    }

    // ---- reduce over the 16 doc lanes, write per-block partials ----
#pragma unroll
    for (int t = 0; t < 12; ++t) {
        racc[t] += __shfl_xor(racc[t], 1, 64);
        racc[t] += __shfl_xor(racc[t], 2, 64);
        racc[t] += __shfl_xor(racc[t], 4, 64);
        racc[t] += __shfl_xor(racc[t], 8, 64);
    }
    if ((lane & 15) == 0) {
        const int kb = g * 3;
#pragma unroll
        for (int j = 0; j < 3; ++j) {
            if (g < 3 || j < 2) {        // skip the k10 duplicate slot
#pragma unroll
                for (int qq = 0; qq < 4; ++qq)
                    part[blk * (NK * NQ) + (kb + j) * NQ + (w * 4 + qq)] = racc[j * 4 + qq];
            }
        }
    }
}

// ---------------- Kernel 2: sum partials, masked log-sum over q, FC ----------------
__global__ void knrm_final(const float* __restrict__ part,
                           const int*   __restrict__ qtoks,
                           const float* __restrict__ fc_w,
                           const float* __restrict__ fc_b,
                           float*       __restrict__ out) {
    __shared__ float red[NK * NQ];
    __shared__ float ks[NK];
    int b = blockIdx.x;
    int t = threadIdx.x;
    if (t < NK * NQ) {
        int q = t & 15;
        float r = 0.f;
        for (int j = 0; j < BLOCKS_PER_B; ++j)
            r += part[(b * BLOCKS_PER_B + j) * (NK * NQ) + t];
        red[t] = (qtoks[b * NQ + q] != 0) ? logf(r + 1e-6f) : 0.f;
    }
    __syncthreads();
    if (t < NK) {
        float s = 0.f;
        for (int q = 0; q < NQ; ++q) s += red[t * NQ + q];
        ks[t] = s * fc_w[t];
    }
    __syncthreads();
    if (t == 0) {
        float s = fc_b[0];
        for (int k = 0; k < NK; ++k) s += ks[k];
        out[b] = s;
    }
}

extern "C" void kernel_launch(void* const* d_in, const int* in_sizes, int n_in,
                              void* d_out, int out_size, void* d_ws, size_t ws_size,
                              hipStream_t stream) {
    const int*   doctoks   = (const int*)  d_in[0];   // [128,1024]
    const int*   querytoks = (const int*)  d_in[1];   // [128,16]
    // d_in[2] = query_idf: unused by the reference
    const float* emb       = (const float*)d_in[3];   // [100000,300]
    const float* mus       = (const float*)d_in[4];   // [11]
    const float* sigmas    = (const float*)d_in[5];   // [11]
    const float* fc_w      = (const float*)d_in[6];   // [1,11]
    const float* fc_b      = (const float*)d_in[7];   // [1]
    float* out = (float*)d_out;                        // [128]

    float* part = (float*)d_ws;                        // [512][176] floats

    knrm_main<<<NB * BLOCKS_PER_B, BLOCK, 0, stream>>>(doctoks, querytoks, emb,
                                                       mus, sigmas, part);
    knrm_final<<<NB, 192, 0, stream>>>(part, querytoks, fc_w, fc_b, out);
}

// Round 7
// 233.421 us; speedup vs baseline: 1.0927x; 1.0535x over previous
//
#include <hip/hip_runtime.h>

#define EDIM 300
#define NB   128
#define NQ   16
#define ND   1024
#define NK   11
#define BLOCK 256
#define TDOCS 128                 // docs per block
#define BLOCKS_PER_B 8            // 1024 / 128
#define DTILE 8                   // docs per staged tile (full 300-float rows)
#define NTILE 16                  // TDOCS / DTILE
#define NF4   75                  // float4 per embedding row (300/4)

// R15: maximize per-CU MLP via independent blocks. Evidence: every >=1.3 TB/s
// run had 2 independent blocks/CU; R14's single-block/CU (correct pipeline!)
// fell to 0.86 TB/s. Granularity (full rows) and intra-block scheduling were
// both ~neutral -> gather BW scales with INDEPENDENT barrier domains per CU.
// This round: 128 docs/block, 1024 blocks = 4 blocks/CU x 256 CU; LDS 38.9 KB
// (qn 19.2 + 2x dpan[8 rows] 19.2 + dtok 0.5) -> 4 blocks/CU, 16 waves/CU.
// qnorm hoisted to a pre-kernel (qn_ws in workspace) so the 8x-replicated
// prologue is gone. Staging keeps full-row gload_lds + R14's (correct)
// stage-after-barrier double-buffer.

__device__ __forceinline__ void gload16(const float* g, float* l) {
    __builtin_amdgcn_global_load_lds(
        (const __attribute__((address_space(1))) void*)g,
        (__attribute__((address_space(3))) void*)l, 16, 0, 0);
}

// ---------------- Kernel 0: gather + normalize q rows into qn_ws ----------------
__global__ __launch_bounds__(BLOCK) void knrm_qnorm(
    const int* __restrict__ qtoks, const float* __restrict__ emb,
    float* __restrict__ qn_ws) {
    __shared__ __align__(16) float qn_s[NQ * EDIM];
    __shared__ float rs_s[NQ];
    const int b = blockIdx.x, tid = threadIdx.x, lane = tid & 63, w = tid >> 6;
#pragma unroll
    for (int i = 0; i < 5; ++i) {                        // 1200 f4 slots, 300/wave
        int fi = w * 300 + i * 64 + lane;
        if (i < 4 || lane < 44) {
            int q = fi / NF4, e4 = fi - q * NF4;
            gload16(emb + (size_t)qtoks[b * NQ + q] * EDIM + e4 * 4, qn_s + fi * 4);
        }
    }
    __syncthreads();
    {   // q norms: 16 lanes per q
        int q = tid >> 4, j = tid & 15;
        float ss = 0.f;
        for (int e = j; e < EDIM; e += 16) { float v = qn_s[q * EDIM + e]; ss += v * v; }
        ss += __shfl_xor(ss, 1, 64);
        ss += __shfl_xor(ss, 2, 64);
        ss += __shfl_xor(ss, 4, 64);
        ss += __shfl_xor(ss, 8, 64);
        if (j == 0) rs_s[q] = 1.0f / (sqrtf(ss) + 1e-9f);
    }
    __syncthreads();
    float4* dst = (float4*)(qn_ws + (size_t)b * NQ * EDIM);
    for (int i = tid; i < NQ * NF4; i += BLOCK) {
        float4 v = ((float4*)qn_s)[i];
        float r = rs_s[i / NF4];
        v.x *= r; v.y *= r; v.z *= r; v.w *= r;
        dst[i] = v;
    }
}

// ---------------- Kernel 1: doc gather + sim + RBF partials ----------------
__global__ __launch_bounds__(BLOCK, 4) void knrm_main(
    const int*   __restrict__ dtoks,
    const float* __restrict__ qn_ws,
    const float* __restrict__ emb,
    const float* __restrict__ mus,
    const float* __restrict__ sigmas,
    float*       __restrict__ part) {
    __shared__ __align__(16) float qn_s[NQ * EDIM];        // 19.2 KB
    __shared__ __align__(16) float dpan[2][DTILE * EDIM];  // 19.2 KB
    __shared__ int dtok_s[TDOCS];                          // 0.5 KB
    // total ~38.9 KB -> 4 blocks/CU, 16 waves/CU

    const int blk   = blockIdx.x;
    const int b     = blk >> 3;
    const int dbase = (blk & 7) * TDOCS;
    const int tid   = threadIdx.x;
    const int lane  = tid & 63;
    const int w     = tid >> 6;          // q-quad: this wave handles q = w*4+qq

    if (tid < TDOCS) dtok_s[tid] = dtoks[b * ND + dbase + tid];
    const float* qsrc = qn_ws + (size_t)b * NQ * EDIM;
#pragma unroll
    for (int i = 0; i < 5; ++i) {                        // stream qn_ws -> LDS
        int fi = w * 300 + i * 64 + lane;
        if (i < 4 || lane < 44) gload16(qsrc + fi * 4, qn_s + fi * 4);
    }
    __syncthreads();                     // dtok_s visible; qn loads drained

    // stage(tb -> dst): 8 rows * 75 f4 = 600 slots; 150/wave (3 instrs, last lane<22)
#define STAGE(tb, dst) do {                                                    \
    _Pragma("unroll")                                                          \
    for (int i_ = 0; i_ < 3; ++i_) {                                           \
        if (i_ < 2 || lane < 22) {                                             \
            int fi_ = w * 150 + i_ * 64 + lane;                                \
            int r_ = fi_ / NF4, e4_ = fi_ - r_ * NF4;                          \
            gload16(emb + (size_t)dtok_s[(tb) * DTILE + r_] * EDIM + e4_ * 4,  \
                    (dst) + fi_ * 4);                                          \
        }                                                                      \
    } } while (0)

    STAGE(0, dpan[0]);                   // exposed once per block; overlapped by
                                         // the 3 sibling blocks on this CU

    // ---- per-thread roles ----
    const int d = lane & 7;              // doc within tile
    const int g = lane >> 3;             // E-eighth AND kernel group (0..7)
    const float mua = mus[g];
    const float sga = sigmas[g];
    const float c2a = -0.5f / (sga * sga);
    const int   kb  = (8 + g > NK - 1) ? NK - 1 : 8 + g;  // g<3 -> kernels 8,9,10
    const float mub = mus[kb];
    const float sgb = sigmas[kb];
    const float c2b = -0.5f / (sgb * sgb);

    float ra0 = 0.f, ra1 = 0.f, ra2 = 0.f, ra3 = 0.f;
    float rb0 = 0.f, rb1 = 0.f, rb2 = 0.f, rb3 = 0.f;

    for (int tb = 0; tb < NTILE; ++tb) {
        __syncthreads();                 // stage(tb) landed (free drain: full compute
                                         // phase in flight); other buffer now free
        if (tb + 1 < NTILE)
            STAGE(tb + 1, dpan[(tb + 1) & 1]);   // in flight under compute(tb)

        const float* dr = dpan[tb & 1] + d * EDIM;
        const float* qb = qn_s + (w * 4) * EDIM;
        float sv0 = 0.f, sv1 = 0.f, sv2 = 0.f, sv3 = 0.f, ss = 0.f;
#pragma unroll
        for (int i = 0; i < 10; ++i) {
            int e4 = g * 10 + i;
            if (e4 < NF4) {              // masks only g==7, i>=5
                float4 a  = *(const float4*)(dr + e4 * 4);
                ss += a.x*a.x + a.y*a.y + a.z*a.z + a.w*a.w;
                float4 q0 = *(const float4*)(qb + 0 * EDIM + e4 * 4);
                float4 q1 = *(const float4*)(qb + 1 * EDIM + e4 * 4);
                float4 q2 = *(const float4*)(qb + 2 * EDIM + e4 * 4);
                float4 q3 = *(const float4*)(qb + 3 * EDIM + e4 * 4);
                sv0 += q0.x*a.x + q0.y*a.y + q0.z*a.z + q0.w*a.w;
                sv1 += q1.x*a.x + q1.y*a.y + q1.z*a.z + q1.w*a.w;
                sv2 += q2.x*a.x + q2.y*a.y + q2.z*a.z + q2.w*a.w;
                sv3 += q3.x*a.x + q3.y*a.y + q3.z*a.z + q3.w*a.w;
            }
        }
        // combine the 8 E-eighths (xor 8,16,32 stay in-wave)
        ss  += __shfl_xor(ss, 8, 64);  ss  += __shfl_xor(ss, 16, 64);  ss  += __shfl_xor(ss, 32, 64);
        sv0 += __shfl_xor(sv0, 8, 64); sv0 += __shfl_xor(sv0, 16, 64); sv0 += __shfl_xor(sv0, 32, 64);
        sv1 += __shfl_xor(sv1, 8, 64); sv1 += __shfl_xor(sv1, 16, 64); sv1 += __shfl_xor(sv1, 32, 64);
        sv2 += __shfl_xor(sv2, 8, 64); sv2 += __shfl_xor(sv2, 16, 64); sv2 += __shfl_xor(sv2, 32, 64);
        sv3 += __shfl_xor(sv3, 8, 64); sv3 += __shfl_xor(sv3, 16, 64); sv3 += __shfl_xor(sv3, 32, 64);
        const float rn = 1.0f / (sqrtf(ss) + 1e-9f);
        const float s0 = sv0 * rn, s1 = sv1 * rn, s2 = sv2 * rn, s3 = sv3 * rn;
        // RBF: group g handles kernel g (all) and kernel 8+g (g<3; others masked at write)
        float e;
        e = s0 - mua; ra0 += __expf(c2a * e * e);
        e = s1 - mua; ra1 += __expf(c2a * e * e);
        e = s2 - mua; ra2 += __expf(c2a * e * e);
        e = s3 - mua; ra3 += __expf(c2a * e * e);
        e = s0 - mub; rb0 += __expf(c2b * e * e);
        e = s1 - mub; rb1 += __expf(c2b * e * e);
        e = s2 - mub; rb2 += __expf(c2b * e * e);
        e = s3 - mub; rb3 += __expf(c2b * e * e);
        // no bottom barrier: next loop-top barrier covers buffer reuse
    }

    // ---- reduce over the 8 doc lanes (xor 1,2,4), write partials ----
#define RED(x) x += __shfl_xor(x, 1, 64); x += __shfl_xor(x, 2, 64); x += __shfl_xor(x, 4, 64)
    RED(ra0); RED(ra1); RED(ra2); RED(ra3);
    RED(rb0); RED(rb1); RED(rb2); RED(rb3);
    if (d == 0) {
        float* po = part + (size_t)blk * (NK * NQ);
        po[g * NQ + (w * 4 + 0)] = ra0;
        po[g * NQ + (w * 4 + 1)] = ra1;
        po[g * NQ + (w * 4 + 2)] = ra2;
        po[g * NQ + (w * 4 + 3)] = ra3;
        if (g < 3) {
            po[(8 + g) * NQ + (w * 4 + 0)] = rb0;
            po[(8 + g) * NQ + (w * 4 + 1)] = rb1;
            po[(8 + g) * NQ + (w * 4 + 2)] = rb2;
            po[(8 + g) * NQ + (w * 4 + 3)] = rb3;
        }
    }
}

// ---------------- Kernel 2: sum partials, masked log-sum over q, FC ----------------
__global__ void knrm_final(const float* __restrict__ part,
                           const int*   __restrict__ qtoks,
                           const float* __restrict__ fc_w,
                           const float* __restrict__ fc_b,
                           float*       __restrict__ out) {
    __shared__ float red[NK * NQ];
    __shared__ float ks[NK];
    int b = blockIdx.x;
    int t = threadIdx.x;
    if (t < NK * NQ) {
        int q = t & 15;
        float r = 0.f;
        for (int j = 0; j < BLOCKS_PER_B; ++j)
            r += part[(size_t)(b * BLOCKS_PER_B + j) * (NK * NQ) + t];
        red[t] = (qtoks[b * NQ + q] != 0) ? logf(r + 1e-6f) : 0.f;
    }
    __syncthreads();
    if (t < NK) {
        float s = 0.f;
        for (int q = 0; q < NQ; ++q) s += red[t * NQ + q];
        ks[t] = s * fc_w[t];
    }
    __syncthreads();
    if (t == 0) {
        float s = fc_b[0];
        for (int k = 0; k < NK; ++k) s += ks[k];
        out[b] = s;
    }
}

extern "C" void kernel_launch(void* const* d_in, const int* in_sizes, int n_in,
                              void* d_out, int out_size, void* d_ws, size_t ws_size,
                              hipStream_t stream) {
    const int*   doctoks   = (const int*)  d_in[0];   // [128,1024]
    const int*   querytoks = (const int*)  d_in[1];   // [128,16]
    // d_in[2] = query_idf: unused by the reference
    const float* emb       = (const float*)d_in[3];   // [100000,300]
    const float* mus       = (const float*)d_in[4];   // [11]
    const float* sigmas    = (const float*)d_in[5];   // [11]
    const float* fc_w      = (const float*)d_in[6];   // [1,11]
    const float* fc_b      = (const float*)d_in[7];   // [1]
    float* out = (float*)d_out;                        // [128]

    float* part  = (float*)d_ws;                               // 1024*176 floats (~721 KB)
    float* qn_ws = (float*)((char*)d_ws + (1 << 20));          // 128*16*300 floats (~2.46 MB)

    knrm_qnorm<<<NB, BLOCK, 0, stream>>>(querytoks, emb, qn_ws);
    knrm_main<<<NB * BLOCKS_PER_B, BLOCK, 0, stream>>>(doctoks, qn_ws, emb,
                                                       mus, sigmas, part);
    knrm_final<<<NB, 192, 0, stream>>>(part, querytoks, fc_w, fc_b, out);
}